// Round 6
// baseline (207.006 us; speedup 1.0000x reference)
//
#include <hip/hip_runtime.h>
#include <hip/hip_bf16.h>
#include <cstdint>
#include <cstddef>

#define DD 768
#define TSCALE 20.0f

typedef short bf16x8 __attribute__((ext_vector_type(8)));
typedef float f32x4 __attribute__((ext_vector_type(4)));
typedef int   i32x4 __attribute__((ext_vector_type(4)));

__device__ inline float wsum(float v){
  #pragma unroll
  for (int m = 1; m < 64; m <<= 1) v += __shfl_xor(v, m, 64);
  return v;
}
__device__ inline float wmax(float v){
  #pragma unroll
  for (int m = 1; m < 64; m <<= 1) v = fmaxf(v, __shfl_xor(v, m, 64));
  return v;
}

__device__ inline void gload_lds16(const void* g, void* l){
  __builtin_amdgcn_global_load_lds(
      (const __attribute__((address_space(1))) uint32_t*)g,
      (__attribute__((address_space(3))) uint32_t*)l, 16, 0, 0);
}

__device__ inline void store_bf16x4(__hip_bfloat16* p, float4 x){
  __hip_bfloat16 t[4] = {__float2bfloat16(x.x), __float2bfloat16(x.y),
                         __float2bfloat16(x.z), __float2bfloat16(x.w)};
  *(ushort4*)p = *(const ushort4*)t;
}

// quantize 4 normalized floats (|x|<=1) to int8 at scale 127, packed store
__device__ inline void store_i8x4(int8_t* p, float4 x){
  int q0 = __float2int_rn(x.x * 127.f), q1 = __float2int_rn(x.y * 127.f);
  int q2 = __float2int_rn(x.z * 127.f), q3 = __float2int_rn(x.w * 127.f);
  uint32_t w = (uint32_t)(uint8_t)(int8_t)q0 | ((uint32_t)(uint8_t)(int8_t)q1 << 8) |
               ((uint32_t)(uint8_t)(int8_t)q2 << 16) | ((uint32_t)(uint8_t)(int8_t)q3 << 24);
  *(uint32_t*)p = w;
}

// ============ fused: normalize (fp32-exact) + diag argmax/mask + te/ve + i8 emit ======
// One 64-thread block per video i. Produces: obji8/argi8 (wpg GEMM operands),
// diagmax (exact label logits), tenb/venb (bf16 for ec GEMM).
__global__ __launch_bounds__(64) void diag_teve(
    const float* __restrict__ obj, const float* __restrict__ txt,
    float* __restrict__ diagmax,
    int8_t* __restrict__ obji8, int8_t* __restrict__ argi8,
    __hip_bfloat16* __restrict__ tenb, __hip_bfloat16* __restrict__ venb)
{
  __shared__ float so[8][DD];
  int i = blockIdx.x, lane = threadIdx.x;
  const float* ob = obj + (size_t)i * 8 * DD;
  for (int k = 0; k < 8; ++k){
    float4 v[3]; float ss = 0.f;
    #pragma unroll
    for (int q = 0; q < 3; ++q){
      v[q] = ((const float4*)(ob + k * DD))[lane + q * 64];
      ss += v[q].x * v[q].x + v[q].y * v[q].y + v[q].z * v[q].z + v[q].w * v[q].w;
    }
    ss = wsum(ss);
    float inv = 1.0f / fmaxf(sqrtf(ss), 1e-12f);
    #pragma unroll
    for (int q = 0; q < 3; ++q){
      float4 x = {v[q].x * inv, v[q].y * inv, v[q].z * inv, v[q].w * inv};
      ((float4*)&so[k][0])[lane + q * 64] = x;
      store_i8x4(obji8 + (size_t)(i * 8 + k) * DD + 4 * (lane + q * 64), x);
    }
  }
  __syncthreads();

  float4 te[3], ve[3];
  {
    const float* t1 = txt + ((size_t)i * 4 + 1) * DD;
    float ss = 0.f;
    #pragma unroll
    for (int q = 0; q < 3; ++q){
      te[q] = ((const float4*)t1)[lane + q * 64];
      ss += te[q].x * te[q].x + te[q].y * te[q].y + te[q].z * te[q].z + te[q].w * te[q].w;
    }
    ss = wsum(ss);
    float inv = 1.0f / fmaxf(sqrtf(ss), 1e-12f);
    #pragma unroll
    for (int q = 0; q < 3; ++q){
      te[q].x *= inv; te[q].y *= inv; te[q].z *= inv; te[q].w *= inv;
      ve[q] = (float4){0.f, 0.f, 0.f, 0.f};
    }
  }

  for (int j = 0; j < 3; ++j){
    int rr = i * 3 + j;
    int s4 = (j == 0) ? 0 : (j + 1);
    const float* ap = txt + ((size_t)i * 4 + s4) * DD;
    float4 a[3]; float ss = 0.f;
    #pragma unroll
    for (int q = 0; q < 3; ++q){
      a[q] = ((const float4*)ap)[lane + q * 64];
      ss += a[q].x * a[q].x + a[q].y * a[q].y + a[q].z * a[q].z + a[q].w * a[q].w;
    }
    ss = wsum(ss);
    float inv = 1.0f / fmaxf(sqrtf(ss), 1e-12f);
    #pragma unroll
    for (int q = 0; q < 3; ++q){
      a[q].x *= inv; a[q].y *= inv; a[q].z *= inv; a[q].w *= inv;
      store_i8x4(argi8 + (size_t)rr * DD + 4 * (lane + q * 64), a[q]);
    }

    float best = -3.0e38f; int bi = 0;
    for (int k = 0; k < 8; ++k){
      float s = 0.f;
      #pragma unroll
      for (int q = 0; q < 3; ++q){
        float4 w = ((const float4*)&so[k][0])[lane + q * 64];
        s += a[q].x * w.x + a[q].y * w.y + a[q].z * w.z + a[q].w * w.w;
      }
      s = wsum(s);
      if (s > best){ best = s; bi = k; }   // strict > == first-index tie rule
    }
    float dm = best * TSCALE;
    if (lane == 0) diagmax[rr] = dm;
    if (dm > 1.0f){                         // wave-uniform (wsum broadcast)
      #pragma unroll
      for (int q = 0; q < 3; ++q){
        float4 w = ((const float4*)&so[bi][0])[lane + q * 64];
        te[q].x += a[q].x; te[q].y += a[q].y; te[q].z += a[q].z; te[q].w += a[q].w;
        ve[q].x += w.x;    ve[q].y += w.y;    ve[q].z += w.z;    ve[q].w += w.w;
      }
    }
  }
  float ss = 0.f;
  #pragma unroll
  for (int q = 0; q < 3; ++q)
    ss += te[q].x * te[q].x + te[q].y * te[q].y + te[q].z * te[q].z + te[q].w * te[q].w;
  ss = wsum(ss);
  float inv = 1.0f / fmaxf(sqrtf(ss), 1e-12f);
  #pragma unroll
  for (int q = 0; q < 3; ++q){
    float4 x = {te[q].x * inv, te[q].y * inv, te[q].z * inv, te[q].w * inv};
    store_bf16x4(tenb + (size_t)i * DD + lane * 4 + q * 256, x);
  }
  ss = 0.f;
  #pragma unroll
  for (int q = 0; q < 3; ++q)
    ss += ve[q].x * ve[q].x + ve[q].y * ve[q].y + ve[q].z * ve[q].z + ve[q].w * ve[q].w;
  ss = wsum(ss);
  inv = 1.0f / fmaxf(sqrtf(ss), 1e-12f);
  #pragma unroll
  for (int q = 0; q < 3; ++q){
    float4 x = {ve[q].x * inv, ve[q].y * inv, ve[q].z * inv, ve[q].w * inv};
    store_bf16x4(venb + (size_t)i * DD + lane * 4 + q * 256, x);
  }
}

// ===================== wpg GEMM, int8: 256x128 tile, BK=64, 2 blocks/CU ===========
// A = argi8 [3840,768], B = obji8 [10240,768]. logits = (A.B^T)*20/127^2.
// Fused: sumexp[row] += sum_col exp(logit - 20).
// LDS 48 KiB: A[2 buf][256x64B] @0/16K, B[2 buf][128x64B] @32K/40K.
// Swizzle: 16B chunk c' = kg ^ ((row>>1)&3), applied on global src + LDS read.
#define AOFF(p) ((p) * 16384)
#define BOFF(p) (32768 + (p) * 8192)
#define MFMAI8(d, av, bv) d = __builtin_amdgcn_mfma_i32_16x16x64_i8(av, bv, d, 0, 0, 0)

__global__ __launch_bounds__(512, 4) void wpg_gemm_i8(
    const int8_t* __restrict__ A, const int8_t* __restrict__ B,
    float* __restrict__ sumexp)
{
  __shared__ char lds[49152];
  const int tid = threadIdx.x;
  const int lane = tid & 63, wid = tid >> 6;
  const int wr = wid >> 2, wc = wid & 3;        // 2 (M) x 4 (N) waves
  const int r = lane & 15, kg = lane >> 4;

  // XCD-chunked swizzle: nxb=80, 10 bx per XCD
  int g = blockIdx.x;
  int bx = (g & 7) * 10 + (g >> 3) % 10;
  int by = (g >> 3) / 10;

  const int8_t* Abase = A + (size_t)by * 256 * DD;
  const int8_t* Bbase = B + (size_t)bx * 128 * DD;

  const int srow = tid >> 2, scl = tid & 3;
  const int ssw = ((scl ^ ((srow >> 1) & 3)) * 16);

  auto STAGE_A = [&](int p, int h, int kt){
    gload_lds16(Abase + (size_t)(h * 128 + srow) * DD + kt * 64 + ssw,
                lds + AOFF(p) + h * 8192 + tid * 16);
  };
  auto STAGE_B = [&](int p, int kt){
    gload_lds16(Bbase + (size_t)srow * DD + kt * 64 + ssw,
                lds + BOFF(p) + tid * 16);
  };
  const int rsw = (r >> 1) & 3;
  auto LDA = [&](int p, int mi)->i32x4 {
    return *(const i32x4*)(lds + AOFF(p) + (wr * 128 + mi * 16 + r) * 64 + ((kg ^ rsw) * 16));
  };
  auto LDB = [&](int p, int ni)->i32x4 {
    return *(const i32x4*)(lds + BOFF(p) + (wc * 32 + ni * 16 + r) * 64 + ((kg ^ rsw) * 16));
  };

  i32x4 acc[8][2];
  #pragma unroll
  for (int mi = 0; mi < 8; ++mi){ acc[mi][0] = (i32x4){0,0,0,0}; acc[mi][1] = (i32x4){0,0,0,0}; }

  // prologue: tile 0 -> buf0
  STAGE_A(0, 0, 0); STAGE_A(0, 1, 0); STAGE_B(0, 0);
  asm volatile("s_waitcnt vmcnt(0)" ::: "memory");
  __builtin_amdgcn_s_barrier();
  __builtin_amdgcn_sched_barrier(0);

  for (int t = 0; t < 12; ++t){
    const int p = t & 1;
    if (t < 11){ STAGE_A(p ^ 1, 0, t + 1); STAGE_A(p ^ 1, 1, t + 1); STAGE_B(p ^ 1, t + 1); }
    i32x4 a[4], b0, b1;
    b0 = LDB(p, 0); b1 = LDB(p, 1);
    #pragma unroll
    for (int mi = 0; mi < 4; ++mi) a[mi] = LDA(p, mi);
    __builtin_amdgcn_s_setprio(1);
    #pragma unroll
    for (int mi = 0; mi < 4; ++mi){ MFMAI8(acc[mi][0], a[mi], b0); MFMAI8(acc[mi][1], a[mi], b1); }
    __builtin_amdgcn_s_setprio(0);
    #pragma unroll
    for (int mi = 0; mi < 4; ++mi) a[mi] = LDA(p, 4 + mi);
    __builtin_amdgcn_s_setprio(1);
    #pragma unroll
    for (int mi = 0; mi < 4; ++mi){ MFMAI8(acc[4 + mi][0], a[mi], b0); MFMAI8(acc[4 + mi][1], a[mi], b1); }
    __builtin_amdgcn_s_setprio(0);
    asm volatile("s_waitcnt vmcnt(0)" ::: "memory");
    __builtin_amdgcn_s_barrier();
    __builtin_amdgcn_sched_barrier(0);
  }

  // epilogue: dequant + per-row sum of exp(logit-20). C layout: col=lane&15, row=kg*4+reg.
  const float SC = TSCALE / 16129.0f;   // 20/127^2
  const int rowbase = by * 256 + wr * 128 + kg * 4;
  #pragma unroll
  for (int mi = 0; mi < 8; ++mi){
    #pragma unroll
    for (int rr = 0; rr < 4; ++rr){
      float s = expf(fmaf((float)acc[mi][0][rr], SC, -TSCALE))
              + expf(fmaf((float)acc[mi][1][rr], SC, -TSCALE));
      s += __shfl_xor(s, 1, 64); s += __shfl_xor(s, 2, 64);
      s += __shfl_xor(s, 4, 64); s += __shfl_xor(s, 8, 64);
      if (r == 0) atomicAdd(&sumexp[rowbase + mi * 16 + rr], s);
    }
  }
}

// ec: A=tenb, B=venb [NB,768] bf16; fused row/col exp-sums + diag capture.
__global__ __launch_bounds__(256) void ec_gemm_mfma(
    const __hip_bfloat16* __restrict__ A, const __hip_bfloat16* __restrict__ B,
    float* __restrict__ rowsum, float* __restrict__ colsum, float* __restrict__ Ldiag)
{
  __shared__ __hip_bfloat16 As[128 * 32];
  __shared__ __hip_bfloat16 Bs[128 * 32];
  int tid = threadIdx.x;
  int bx = blockIdx.x, by = blockIdx.y;
  int wid = tid >> 6, lane = tid & 63;
  int wr = wid >> 1, wc = wid & 1;

  f32x4 acc[4][4];
  #pragma unroll
  for (int i = 0; i < 4; ++i)
    #pragma unroll
    for (int j = 0; j < 4; ++j) acc[i][j] = (f32x4){0.f, 0.f, 0.f, 0.f};

  const char* Ab = (const char*)(A + (size_t)(by * 128) * DD);
  const char* Bb = (const char*)(B + (size_t)(bx * 128) * DD);
  int srow = tid >> 2;
  int scol = (tid & 3) * 16;
  char* AsB = (char*)As; char* BsB = (char*)Bs;
  int r = lane & 15, kg = (lane >> 4) * 8;

  for (int kb = 0; kb < DD * 2; kb += 64){
    gload_lds16(Ab + (size_t)srow * (DD*2) + kb + scol, AsB + tid * 16);
    gload_lds16(Ab + (size_t)(srow + 64) * (DD*2) + kb + scol, AsB + 4096 + tid * 16);
    gload_lds16(Bb + (size_t)srow * (DD*2) + kb + scol, BsB + tid * 16);
    gload_lds16(Bb + (size_t)(srow + 64) * (DD*2) + kb + scol, BsB + 4096 + tid * 16);
    __syncthreads();
    bf16x8 af[4], bfr[4];
    #pragma unroll
    for (int mi = 0; mi < 4; ++mi)
      af[mi] = *(const bf16x8*)&As[(wr * 64 + mi * 16 + r) * 32 + kg];
    #pragma unroll
    for (int ni = 0; ni < 4; ++ni)
      bfr[ni] = *(const bf16x8*)&Bs[(wc * 64 + ni * 16 + r) * 32 + kg];
    #pragma unroll
    for (int mi = 0; mi < 4; ++mi)
      #pragma unroll
      for (int ni = 0; ni < 4; ++ni)
        acc[mi][ni] = __builtin_amdgcn_mfma_f32_16x16x32_bf16(af[mi], bfr[ni], acc[mi][ni], 0, 0, 0);
    __syncthreads();
  }
  int rowbase = by * 128 + wr * 64 + ((lane >> 4) << 2);
  float colacc[4] = {0.f, 0.f, 0.f, 0.f};
  #pragma unroll
  for (int mi = 0; mi < 4; ++mi){
    #pragma unroll
    for (int rr = 0; rr < 4; ++rr){
      float s = 0.f;
      #pragma unroll
      for (int ni = 0; ni < 4; ++ni){
        float e = expf(fmaf(acc[mi][ni][rr], TSCALE, -TSCALE));
        s += e; colacc[ni] += e;
      }
      s += __shfl_xor(s, 1, 64); s += __shfl_xor(s, 2, 64);
      s += __shfl_xor(s, 4, 64); s += __shfl_xor(s, 8, 64);
      if ((lane & 15) == 0) atomicAdd(&rowsum[rowbase + mi * 16 + rr], s);
    }
  }
  #pragma unroll
  for (int ni = 0; ni < 4; ++ni){
    float c = colacc[ni];
    c += __shfl_xor(c, 16, 64); c += __shfl_xor(c, 32, 64);
    if (lane < 16) atomicAdd(&colsum[bx * 128 + wc * 64 + ni * 16 + lane], c);
  }
  if (bx == by){
    #pragma unroll
    for (int mi = 0; mi < 4; ++mi)
      #pragma unroll
      for (int ni = 0; ni < 4; ++ni)
        #pragma unroll
        for (int rr = 0; rr < 4; ++rr){
          int grow = wr * 64 + mi * 16 + ((lane >> 4) << 2) + rr;
          int gcol = wc * 64 + ni * 16 + (lane & 15);
          if (grow == gcol) Ldiag[by * 128 + grow] = acc[mi][ni][rr] * TSCALE;
        }
  }
}

__global__ __launch_bounds__(64) void lossv_kernel(
    const float* __restrict__ mdl, const int* __restrict__ lab,
    float* __restrict__ acc, int C)
{
  int row = blockIdx.x, lane = threadIdx.x;
  const float* x = mdl + (size_t)row * C;
  float mx = -3.0e38f;
  for (int c = lane; c < C; c += 64) mx = fmaxf(mx, x[c]);
  mx = wmax(mx);
  float s = 0.f;
  for (int c = lane; c < C; c += 64) s += expf(x[c] - mx);
  s = wsum(s);
  if (lane == 0) atomicAdd(acc, logf(s) + mx - x[lab[row]]);
}

__global__ __launch_bounds__(256) void finalize_kernel(
    const float* __restrict__ sumexp, const float* __restrict__ diagmax,
    const float* __restrict__ rowsum, const float* __restrict__ colsum,
    const float* __restrict__ Ldiag, const float* __restrict__ lossv,
    float* __restrict__ out, int NB)
{
  int tid = threadIdx.x;
  float p = 0.f;
  for (int r = tid; r < 3 * NB; r += 256) p += logf(sumexp[r]) + TSCALE - diagmax[r];
  p *= (0.3f / (3.0f * NB));
  float q = 0.f;
  for (int i2 = tid; i2 < NB; i2 += 256)
    q += (logf(rowsum[i2]) + TSCALE - Ldiag[i2]) + (logf(colsum[i2]) + TSCALE - Ldiag[i2]);
  p += q * (0.25f / NB);
  __shared__ float red[256];
  red[tid] = p; __syncthreads();
  for (int s = 128; s > 0; s >>= 1){ if (tid < s) red[tid] += red[tid + s]; __syncthreads(); }
  if (tid == 0) out[0] = red[0] + 0.2f * (lossv[0] / NB);
}

extern "C" void kernel_launch(void* const* d_in, const int* in_sizes, int n_in,
                              void* d_out, int out_size, void* d_ws, size_t ws_size,
                              hipStream_t stream) {
  const float* obj = (const float*)d_in[0];
  const float* txt = (const float*)d_in[1];
  const float* mdl = (const float*)d_in[2];
  const int*   lab = (const int*)d_in[3];

  const int NB = in_sizes[1] / (4 * DD);   // 1280
  const int C  = in_sizes[2] / NB;          // 504

  float* ws = (float*)d_ws;
  size_t o = 0;
  int8_t* obji8 = (int8_t*)(ws + o); o += (size_t)NB * 8 * DD / 4;   // bytes/4
  int8_t* argi8 = (int8_t*)(ws + o); o += (size_t)NB * 3 * DD / 4;
  __hip_bfloat16* tenb = (__hip_bfloat16*)(ws + o); o += (size_t)NB * DD / 2;
  __hip_bfloat16* venb = (__hip_bfloat16*)(ws + o); o += (size_t)NB * DD / 2;
  float* diagmax = ws + o; o += (size_t)3 * NB;
  float* Ldiag = ws + o; o += (size_t)NB;
  float* zr = ws + o;
  float* sumexp = zr;                      // 3*NB
  float* rowsum = zr + 3 * NB;             // NB
  float* colsum = rowsum + NB;             // NB
  float* lossv  = colsum + NB;             // 1

  hipMemsetAsync(zr, 0, (size_t)(5 * NB + 1) * sizeof(float), stream);

  diag_teve<<<NB, 64, 0, stream>>>(obj, txt, diagmax, obji8, argi8, tenb, venb);
  wpg_gemm_i8<<<(NB * 3 / 256) * (NB * 8 / 128), 512, 0, stream>>>(argi8, obji8, sumexp);
  ec_gemm_mfma<<<dim3(NB / 128, NB / 128), 256, 0, stream>>>(tenb, venb, rowsum, colsum, Ldiag);
  lossv_kernel<<<NB, 64, 0, stream>>>(mdl, lab, lossv, C);
  finalize_kernel<<<1, 256, 0, stream>>>(sumexp, diagmax, rowsum, colsum, Ldiag, lossv,
                                         (float*)d_out, NB);
}

// Round 7
// 157.278 us; speedup vs baseline: 1.3162x; 1.3162x over previous
//
#include <hip/hip_runtime.h>
#include <hip/hip_bf16.h>
#include <cstdint>
#include <cstddef>

#define DD 768
#define TSCALE 20.0f

typedef short bf16x8 __attribute__((ext_vector_type(8)));
typedef float f32x4 __attribute__((ext_vector_type(4)));
typedef int   i32x4 __attribute__((ext_vector_type(4)));

__device__ inline float wsum(float v){
  #pragma unroll
  for (int m = 1; m < 64; m <<= 1) v += __shfl_xor(v, m, 64);
  return v;
}
__device__ inline float wmax(float v){
  #pragma unroll
  for (int m = 1; m < 64; m <<= 1) v = fmaxf(v, __shfl_xor(v, m, 64));
  return v;
}

__device__ inline void gload_lds16(const void* g, void* l){
  __builtin_amdgcn_global_load_lds(
      (const __attribute__((address_space(1))) uint32_t*)g,
      (__attribute__((address_space(3))) uint32_t*)l, 16, 0, 0);
}

__device__ inline void store_bf16x4(__hip_bfloat16* p, float4 x){
  __hip_bfloat16 t[4] = {__float2bfloat16(x.x), __float2bfloat16(x.y),
                         __float2bfloat16(x.z), __float2bfloat16(x.w)};
  *(ushort4*)p = *(const ushort4*)t;
}

// quantize 4 normalized floats (|x|<=1) to int8 at scale 127, packed store
__device__ inline void store_i8x4(int8_t* p, float4 x){
  int q0 = __float2int_rn(x.x * 127.f), q1 = __float2int_rn(x.y * 127.f);
  int q2 = __float2int_rn(x.z * 127.f), q3 = __float2int_rn(x.w * 127.f);
  uint32_t w = (uint32_t)(uint8_t)(int8_t)q0 | ((uint32_t)(uint8_t)(int8_t)q1 << 8) |
               ((uint32_t)(uint8_t)(int8_t)q2 << 16) | ((uint32_t)(uint8_t)(int8_t)q3 << 24);
  *(uint32_t*)p = w;
}

// ============ fused: normalize (fp32-exact) + diag argmax/mask + te/ve + i8 emit ======
__global__ __launch_bounds__(64) void diag_teve(
    const float* __restrict__ obj, const float* __restrict__ txt,
    float* __restrict__ diagmax,
    int8_t* __restrict__ obji8, int8_t* __restrict__ argi8,
    __hip_bfloat16* __restrict__ tenb, __hip_bfloat16* __restrict__ venb)
{
  __shared__ float so[8][DD];
  int i = blockIdx.x, lane = threadIdx.x;
  const float* ob = obj + (size_t)i * 8 * DD;
  for (int k = 0; k < 8; ++k){
    float4 v[3]; float ss = 0.f;
    #pragma unroll
    for (int q = 0; q < 3; ++q){
      v[q] = ((const float4*)(ob + k * DD))[lane + q * 64];
      ss += v[q].x * v[q].x + v[q].y * v[q].y + v[q].z * v[q].z + v[q].w * v[q].w;
    }
    ss = wsum(ss);
    float inv = 1.0f / fmaxf(sqrtf(ss), 1e-12f);
    #pragma unroll
    for (int q = 0; q < 3; ++q){
      float4 x = {v[q].x * inv, v[q].y * inv, v[q].z * inv, v[q].w * inv};
      ((float4*)&so[k][0])[lane + q * 64] = x;
      store_i8x4(obji8 + (size_t)(i * 8 + k) * DD + 4 * (lane + q * 64), x);
    }
  }
  __syncthreads();

  float4 te[3], ve[3];
  {
    const float* t1 = txt + ((size_t)i * 4 + 1) * DD;
    float ss = 0.f;
    #pragma unroll
    for (int q = 0; q < 3; ++q){
      te[q] = ((const float4*)t1)[lane + q * 64];
      ss += te[q].x * te[q].x + te[q].y * te[q].y + te[q].z * te[q].z + te[q].w * te[q].w;
    }
    ss = wsum(ss);
    float inv = 1.0f / fmaxf(sqrtf(ss), 1e-12f);
    #pragma unroll
    for (int q = 0; q < 3; ++q){
      te[q].x *= inv; te[q].y *= inv; te[q].z *= inv; te[q].w *= inv;
      ve[q] = (float4){0.f, 0.f, 0.f, 0.f};
    }
  }

  for (int j = 0; j < 3; ++j){
    int rr = i * 3 + j;
    int s4 = (j == 0) ? 0 : (j + 1);
    const float* ap = txt + ((size_t)i * 4 + s4) * DD;
    float4 a[3]; float ss = 0.f;
    #pragma unroll
    for (int q = 0; q < 3; ++q){
      a[q] = ((const float4*)ap)[lane + q * 64];
      ss += a[q].x * a[q].x + a[q].y * a[q].y + a[q].z * a[q].z + a[q].w * a[q].w;
    }
    ss = wsum(ss);
    float inv = 1.0f / fmaxf(sqrtf(ss), 1e-12f);
    #pragma unroll
    for (int q = 0; q < 3; ++q){
      a[q].x *= inv; a[q].y *= inv; a[q].z *= inv; a[q].w *= inv;
      store_i8x4(argi8 + (size_t)rr * DD + 4 * (lane + q * 64), a[q]);
    }

    float best = -3.0e38f; int bi = 0;
    for (int k = 0; k < 8; ++k){
      float s = 0.f;
      #pragma unroll
      for (int q = 0; q < 3; ++q){
        float4 w = ((const float4*)&so[k][0])[lane + q * 64];
        s += a[q].x * w.x + a[q].y * w.y + a[q].z * w.z + a[q].w * w.w;
      }
      s = wsum(s);
      if (s > best){ best = s; bi = k; }   // strict > == first-index tie rule
    }
    float dm = best * TSCALE;
    if (lane == 0) diagmax[rr] = dm;
    if (dm > 1.0f){                         // wave-uniform (wsum broadcast)
      #pragma unroll
      for (int q = 0; q < 3; ++q){
        float4 w = ((const float4*)&so[bi][0])[lane + q * 64];
        te[q].x += a[q].x; te[q].y += a[q].y; te[q].z += a[q].z; te[q].w += a[q].w;
        ve[q].x += w.x;    ve[q].y += w.y;    ve[q].z += w.z;    ve[q].w += w.w;
      }
    }
  }
  float ss = 0.f;
  #pragma unroll
  for (int q = 0; q < 3; ++q)
    ss += te[q].x * te[q].x + te[q].y * te[q].y + te[q].z * te[q].z + te[q].w * te[q].w;
  ss = wsum(ss);
  float inv = 1.0f / fmaxf(sqrtf(ss), 1e-12f);
  #pragma unroll
  for (int q = 0; q < 3; ++q){
    float4 x = {te[q].x * inv, te[q].y * inv, te[q].z * inv, te[q].w * inv};
    store_bf16x4(tenb + (size_t)i * DD + lane * 4 + q * 256, x);
  }
  ss = 0.f;
  #pragma unroll
  for (int q = 0; q < 3; ++q)
    ss += ve[q].x * ve[q].x + ve[q].y * ve[q].y + ve[q].z * ve[q].z + ve[q].w * ve[q].w;
  ss = wsum(ss);
  inv = 1.0f / fmaxf(sqrtf(ss), 1e-12f);
  #pragma unroll
  for (int q = 0; q < 3; ++q){
    float4 x = {ve[q].x * inv, ve[q].y * inv, ve[q].z * inv, ve[q].w * inv};
    store_bf16x4(venb + (size_t)i * DD + lane * 4 + q * 256, x);
  }
}

// ============ wpg GEMM, int8: 256x256 tile, BK=128 (128 B rows), 8-phase ===========
// Byte-geometry identical to the round-5 bf16 kernel (128 rows x 128 B half-tiles,
// chunk-XOR swizzle, counted vmcnt(4)); 6 K-tiles -> 3 iterations.
// logits = (A.B^T) * 20/127^2; fused sumexp[row] += sum_col exp(logit - 20).
#define LDSOFF(buf, mat, half) (((buf) << 16) + ((mat) << 15) + ((half) << 14))
#define MFMAI8(d, av, bv) d = __builtin_amdgcn_mfma_i32_16x16x64_i8(av, bv, d, 0, 0, 0)

__global__ __launch_bounds__(512, 2) void wpg_gemm_i8(
    const int8_t* __restrict__ A, const int8_t* __restrict__ B,
    float* __restrict__ sumexp, int nxb)
{
  __shared__ char lds[131072];
  const int tid = threadIdx.x;
  const int lane = tid & 63, wid = tid >> 6;
  const int wr = wid >> 2, wc = wid & 3;          // 2 x 4 waves
  const int r = lane & 15, kg = lane >> 4;

  // XCD-chunked remap (nxb = 40, 5 bx per XCD)
  int g = blockIdx.x;
  int cpx = nxb >> 3;
  int bx = (g & 7) * cpx + (g >> 3) % cpx;
  int by = (g >> 3) / cpx;

  const int8_t* Abase = A + (size_t)by * 256 * DD;
  const int8_t* Bbase = B + (size_t)bx * 256 * DD;

  const int r0 = tid >> 3,         ch0 = (tid & 7) ^ (r0 & 7);
  const int r1 = (tid + 512) >> 3, ch1 = (tid & 7) ^ (r1 & 7);
  const int c0 = tid, c1 = tid + 512;

  auto STAGE = [&](const int8_t* gbase, int buf, int mat, int half, int kt){
    gload_lds16(gbase + (size_t)(half * 128 + r0) * DD + kt * 128 + ch0 * 16,
                lds + LDSOFF(buf, mat, half) + c0 * 16);
    gload_lds16(gbase + (size_t)(half * 128 + r1) * DD + kt * 128 + ch1 * 16,
                lds + LDSOFF(buf, mat, half) + c1 * 16);
  };
  auto LDA = [&](int buf, int mi, int kk)->i32x4 {
    return *(const i32x4*)(lds + LDSOFF(buf, 0, wr) + (mi * 16 + r) * 128 + (((kk * 4 + kg) ^ (r & 7)) * 16));
  };
  auto LDB = [&](int buf, int ni, int kk)->i32x4 {
    return *(const i32x4*)(lds + LDSOFF(buf, 1, wc >> 1) + ((wc & 1) * 64 + ni * 16 + r) * 128 + (((kk * 4 + kg) ^ (r & 7)) * 16));
  };

  i32x4 acc[8][4];
  #pragma unroll
  for (int i = 0; i < 8; ++i)
    #pragma unroll
    for (int j = 0; j < 4; ++j) acc[i][j] = (i32x4){0, 0, 0, 0};

  i32x4 a[4][2], b0[2][2], b1[2][2];

  // Prologue: tile0 (full, buf0) + tile1 B halves (buf1).
  STAGE(Bbase, 0, 1, 0, 0); STAGE(Bbase, 0, 1, 1, 0);
  STAGE(Abase, 0, 0, 0, 0); STAGE(Abase, 0, 0, 1, 0);
  STAGE(Bbase, 1, 1, 0, 1); STAGE(Bbase, 1, 1, 1, 1);
  asm volatile("s_waitcnt vmcnt(4)" ::: "memory");
  __builtin_amdgcn_s_barrier();
  __builtin_amdgcn_sched_barrier(0);

  for (int it = 0; it < 3; ++it){
    const int t1 = 2 * it + 1;
    const int t2 = (2 * it + 2 < 5) ? 2 * it + 2 : 5;
    const int t3 = (2 * it + 3 < 5) ? 2 * it + 3 : 5;

    // ---- P0: buf0, quad(mi0-3, ni0-1). stage A-h0(t1)->buf1
    #pragma unroll
    for (int mi = 0; mi < 4; ++mi){ a[mi][0] = LDA(0, mi, 0); a[mi][1] = LDA(0, mi, 1); }
    #pragma unroll
    for (int ni = 0; ni < 2; ++ni){ b0[ni][0] = LDB(0, ni, 0); b0[ni][1] = LDB(0, ni, 1); }
    STAGE(Abase, 1, 0, 0, t1);
    __builtin_amdgcn_s_barrier();
    __builtin_amdgcn_s_setprio(1);
    #pragma unroll
    for (int mi = 0; mi < 4; ++mi)
      #pragma unroll
      for (int ni = 0; ni < 2; ++ni){ MFMAI8(acc[mi][ni], a[mi][0], b0[ni][0]); MFMAI8(acc[mi][ni], a[mi][1], b0[ni][1]); }
    __builtin_amdgcn_s_setprio(0);
    __builtin_amdgcn_s_barrier();

    // ---- P1: buf0, quad(mi0-3, ni2-3). stage A-h1(t1)->buf1
    #pragma unroll
    for (int ni = 0; ni < 2; ++ni){ b1[ni][0] = LDB(0, 2 + ni, 0); b1[ni][1] = LDB(0, 2 + ni, 1); }
    STAGE(Abase, 1, 0, 1, t1);
    __builtin_amdgcn_s_barrier();
    __builtin_amdgcn_s_setprio(1);
    #pragma unroll
    for (int mi = 0; mi < 4; ++mi)
      #pragma unroll
      for (int ni = 0; ni < 2; ++ni){ MFMAI8(acc[mi][2 + ni], a[mi][0], b1[ni][0]); MFMAI8(acc[mi][2 + ni], a[mi][1], b1[ni][1]); }
    __builtin_amdgcn_s_setprio(0);
    __builtin_amdgcn_s_barrier();

    // ---- P2: buf0, quad(mi4-7, ni2-3). stage B-h0(t2)->buf0
    #pragma unroll
    for (int mi = 0; mi < 4; ++mi){ a[mi][0] = LDA(0, 4 + mi, 0); a[mi][1] = LDA(0, 4 + mi, 1); }
    STAGE(Bbase, 0, 1, 0, t2);
    __builtin_amdgcn_s_barrier();
    __builtin_amdgcn_s_setprio(1);
    #pragma unroll
    for (int mi = 0; mi < 4; ++mi)
      #pragma unroll
      for (int ni = 0; ni < 2; ++ni){ MFMAI8(acc[4 + mi][2 + ni], a[mi][0], b1[ni][0]); MFMAI8(acc[4 + mi][2 + ni], a[mi][1], b1[ni][1]); }
    __builtin_amdgcn_s_setprio(0);
    __builtin_amdgcn_s_barrier();

    // ---- P3: buf0, quad(mi4-7, ni0-1). stage B-h1(t2)->buf0. vmcnt gate for buf1.
    STAGE(Bbase, 0, 1, 1, t2);
    __builtin_amdgcn_s_barrier();
    __builtin_amdgcn_s_setprio(1);
    #pragma unroll
    for (int mi = 0; mi < 4; ++mi)
      #pragma unroll
      for (int ni = 0; ni < 2; ++ni){ MFMAI8(acc[4 + mi][ni], a[mi][0], b0[ni][0]); MFMAI8(acc[4 + mi][ni], a[mi][1], b0[ni][1]); }
    __builtin_amdgcn_s_setprio(0);
    asm volatile("s_waitcnt vmcnt(4)" ::: "memory");
    __builtin_amdgcn_s_barrier();
    __builtin_amdgcn_sched_barrier(0);

    // ---- P4: buf1, quad(mi0-3, ni0-1). stage A-h0(t2)->buf0
    #pragma unroll
    for (int mi = 0; mi < 4; ++mi){ a[mi][0] = LDA(1, mi, 0); a[mi][1] = LDA(1, mi, 1); }
    #pragma unroll
    for (int ni = 0; ni < 2; ++ni){ b0[ni][0] = LDB(1, ni, 0); b0[ni][1] = LDB(1, ni, 1); }
    STAGE(Abase, 0, 0, 0, t2);
    __builtin_amdgcn_s_barrier();
    __builtin_amdgcn_s_setprio(1);
    #pragma unroll
    for (int mi = 0; mi < 4; ++mi)
      #pragma unroll
      for (int ni = 0; ni < 2; ++ni){ MFMAI8(acc[mi][ni], a[mi][0], b0[ni][0]); MFMAI8(acc[mi][ni], a[mi][1], b0[ni][1]); }
    __builtin_amdgcn_s_setprio(0);
    __builtin_amdgcn_s_barrier();

    // ---- P5: buf1, quad(mi0-3, ni2-3). stage A-h1(t2)->buf0
    #pragma unroll
    for (int ni = 0; ni < 2; ++ni){ b1[ni][0] = LDB(1, 2 + ni, 0); b1[ni][1] = LDB(1, 2 + ni, 1); }
    STAGE(Abase, 0, 0, 1, t2);
    __builtin_amdgcn_s_barrier();
    __builtin_amdgcn_s_setprio(1);
    #pragma unroll
    for (int mi = 0; mi < 4; ++mi)
      #pragma unroll
      for (int ni = 0; ni < 2; ++ni){ MFMAI8(acc[mi][2 + ni], a[mi][0], b1[ni][0]); MFMAI8(acc[mi][2 + ni], a[mi][1], b1[ni][1]); }
    __builtin_amdgcn_s_setprio(0);
    __builtin_amdgcn_s_barrier();

    // ---- P6: buf1, quad(mi4-7, ni2-3). stage B-h0(t3)->buf1
    #pragma unroll
    for (int mi = 0; mi < 4; ++mi){ a[mi][0] = LDA(1, 4 + mi, 0); a[mi][1] = LDA(1, 4 + mi, 1); }
    STAGE(Bbase, 1, 1, 0, t3);
    __builtin_amdgcn_s_barrier();
    __builtin_amdgcn_s_setprio(1);
    #pragma unroll
    for (int mi = 0; mi < 4; ++mi)
      #pragma unroll
      for (int ni = 0; ni < 2; ++ni){ MFMAI8(acc[4 + mi][2 + ni], a[mi][0], b1[ni][0]); MFMAI8(acc[4 + mi][2 + ni], a[mi][1], b1[ni][1]); }
    __builtin_amdgcn_s_setprio(0);
    __builtin_amdgcn_s_barrier();

    // ---- P7: buf1, quad(mi4-7, ni0-1). stage B-h1(t3)->buf1. vmcnt gate for buf0.
    STAGE(Bbase, 1, 1, 1, t3);
    __builtin_amdgcn_s_barrier();
    __builtin_amdgcn_s_setprio(1);
    #pragma unroll
    for (int mi = 0; mi < 4; ++mi)
      #pragma unroll
      for (int ni = 0; ni < 2; ++ni){ MFMAI8(acc[4 + mi][ni], a[mi][0], b0[ni][0]); MFMAI8(acc[4 + mi][ni], a[mi][1], b0[ni][1]); }
    __builtin_amdgcn_s_setprio(0);
    asm volatile("s_waitcnt vmcnt(4)" ::: "memory");
    __builtin_amdgcn_s_barrier();
    __builtin_amdgcn_sched_barrier(0);
  }

  // Epilogue: dequant + per-row sum of exp(logit-20). C layout: col=lane&15, row=kg*4+reg.
  const float SC = TSCALE / 16129.0f;   // 20/127^2
  const int rowbase = by * 256 + wr * 128 + kg * 4;
  #pragma unroll
  for (int mi = 0; mi < 8; ++mi){
    #pragma unroll
    for (int rr = 0; rr < 4; ++rr){
      float s = 0.f;
      #pragma unroll
      for (int ni = 0; ni < 4; ++ni) s += expf(fmaf((float)acc[mi][ni][rr], SC, -TSCALE));
      s += __shfl_xor(s, 1, 64); s += __shfl_xor(s, 2, 64);
      s += __shfl_xor(s, 4, 64); s += __shfl_xor(s, 8, 64);
      if (r == 0) atomicAdd(&sumexp[rowbase + mi * 16 + rr], s);
    }
  }
}

// ec: A=tenb, B=venb [NB,768] bf16; fused row/col exp-sums + diag capture.
__global__ __launch_bounds__(256) void ec_gemm_mfma(
    const __hip_bfloat16* __restrict__ A, const __hip_bfloat16* __restrict__ B,
    float* __restrict__ rowsum, float* __restrict__ colsum, float* __restrict__ Ldiag)
{
  __shared__ __hip_bfloat16 As[128 * 32];
  __shared__ __hip_bfloat16 Bs[128 * 32];
  int tid = threadIdx.x;
  int bx = blockIdx.x, by = blockIdx.y;
  int wid = tid >> 6, lane = tid & 63;
  int wr = wid >> 1, wc = wid & 1;

  f32x4 acc[4][4];
  #pragma unroll
  for (int i = 0; i < 4; ++i)
    #pragma unroll
    for (int j = 0; j < 4; ++j) acc[i][j] = (f32x4){0.f, 0.f, 0.f, 0.f};

  const char* Ab = (const char*)(A + (size_t)(by * 128) * DD);
  const char* Bb = (const char*)(B + (size_t)(bx * 128) * DD);
  int srow = tid >> 2;
  int scol = (tid & 3) * 16;
  char* AsB = (char*)As; char* BsB = (char*)Bs;
  int r = lane & 15, kg = (lane >> 4) * 8;

  for (int kb = 0; kb < DD * 2; kb += 64){
    gload_lds16(Ab + (size_t)srow * (DD*2) + kb + scol, AsB + tid * 16);
    gload_lds16(Ab + (size_t)(srow + 64) * (DD*2) + kb + scol, AsB + 4096 + tid * 16);
    gload_lds16(Bb + (size_t)srow * (DD*2) + kb + scol, BsB + tid * 16);
    gload_lds16(Bb + (size_t)(srow + 64) * (DD*2) + kb + scol, BsB + 4096 + tid * 16);
    __syncthreads();
    bf16x8 af[4], bfr[4];
    #pragma unroll
    for (int mi = 0; mi < 4; ++mi)
      af[mi] = *(const bf16x8*)&As[(wr * 64 + mi * 16 + r) * 32 + kg];
    #pragma unroll
    for (int ni = 0; ni < 4; ++ni)
      bfr[ni] = *(const bf16x8*)&Bs[(wc * 64 + ni * 16 + r) * 32 + kg];
    #pragma unroll
    for (int mi = 0; mi < 4; ++mi)
      #pragma unroll
      for (int ni = 0; ni < 4; ++ni)
        acc[mi][ni] = __builtin_amdgcn_mfma_f32_16x16x32_bf16(af[mi], bfr[ni], acc[mi][ni], 0, 0, 0);
    __syncthreads();
  }
  int rowbase = by * 128 + wr * 64 + ((lane >> 4) << 2);
  float colacc[4] = {0.f, 0.f, 0.f, 0.f};
  #pragma unroll
  for (int mi = 0; mi < 4; ++mi){
    #pragma unroll
    for (int rr = 0; rr < 4; ++rr){
      float s = 0.f;
      #pragma unroll
      for (int ni = 0; ni < 4; ++ni){
        float e = expf(fmaf(acc[mi][ni][rr], TSCALE, -TSCALE));
        s += e; colacc[ni] += e;
      }
      s += __shfl_xor(s, 1, 64); s += __shfl_xor(s, 2, 64);
      s += __shfl_xor(s, 4, 64); s += __shfl_xor(s, 8, 64);
      if ((lane & 15) == 0) atomicAdd(&rowsum[rowbase + mi * 16 + rr], s);
    }
  }
  #pragma unroll
  for (int ni = 0; ni < 4; ++ni){
    float c = colacc[ni];
    c += __shfl_xor(c, 16, 64); c += __shfl_xor(c, 32, 64);
    if (lane < 16) atomicAdd(&colsum[bx * 128 + wc * 64 + ni * 16 + lane], c);
  }
  if (bx == by){
    #pragma unroll
    for (int mi = 0; mi < 4; ++mi)
      #pragma unroll
      for (int ni = 0; ni < 4; ++ni)
        #pragma unroll
        for (int rr = 0; rr < 4; ++rr){
          int grow = wr * 64 + mi * 16 + ((lane >> 4) << 2) + rr;
          int gcol = wc * 64 + ni * 16 + (lane & 15);
          if (grow == gcol) Ldiag[by * 128 + grow] = acc[mi][ni][rr] * TSCALE;
        }
  }
}

__global__ __launch_bounds__(64) void lossv_kernel(
    const float* __restrict__ mdl, const int* __restrict__ lab,
    float* __restrict__ acc, int C)
{
  int row = blockIdx.x, lane = threadIdx.x;
  const float* x = mdl + (size_t)row * C;
  float mx = -3.0e38f;
  for (int c = lane; c < C; c += 64) mx = fmaxf(mx, x[c]);
  mx = wmax(mx);
  float s = 0.f;
  for (int c = lane; c < C; c += 64) s += expf(x[c] - mx);
  s = wsum(s);
  if (lane == 0) atomicAdd(acc, logf(s) + mx - x[lab[row]]);
}

__global__ __launch_bounds__(256) void finalize_kernel(
    const float* __restrict__ sumexp, const float* __restrict__ diagmax,
    const float* __restrict__ rowsum, const float* __restrict__ colsum,
    const float* __restrict__ Ldiag, const float* __restrict__ lossv,
    float* __restrict__ out, int NB)
{
  int tid = threadIdx.x;
  float p = 0.f;
  for (int r = tid; r < 3 * NB; r += 256) p += logf(sumexp[r]) + TSCALE - diagmax[r];
  p *= (0.3f / (3.0f * NB));
  float q = 0.f;
  for (int i2 = tid; i2 < NB; i2 += 256)
    q += (logf(rowsum[i2]) + TSCALE - Ldiag[i2]) + (logf(colsum[i2]) + TSCALE - Ldiag[i2]);
  p += q * (0.25f / NB);
  __shared__ float red[256];
  red[tid] = p; __syncthreads();
  for (int s = 128; s > 0; s >>= 1){ if (tid < s) red[tid] += red[tid + s]; __syncthreads(); }
  if (tid == 0) out[0] = red[0] + 0.2f * (lossv[0] / NB);
}

extern "C" void kernel_launch(void* const* d_in, const int* in_sizes, int n_in,
                              void* d_out, int out_size, void* d_ws, size_t ws_size,
                              hipStream_t stream) {
  const float* obj = (const float*)d_in[0];
  const float* txt = (const float*)d_in[1];
  const float* mdl = (const float*)d_in[2];
  const int*   lab = (const int*)d_in[3];

  const int NB = in_sizes[1] / (4 * DD);   // 1280
  const int C  = in_sizes[2] / NB;          // 504

  float* ws = (float*)d_ws;
  size_t o = 0;
  int8_t* obji8 = (int8_t*)(ws + o); o += (size_t)NB * 8 * DD / 4;   // bytes/4
  int8_t* argi8 = (int8_t*)(ws + o); o += (size_t)NB * 3 * DD / 4;
  __hip_bfloat16* tenb = (__hip_bfloat16*)(ws + o); o += (size_t)NB * DD / 2;
  __hip_bfloat16* venb = (__hip_bfloat16*)(ws + o); o += (size_t)NB * DD / 2;
  float* diagmax = ws + o; o += (size_t)3 * NB;
  float* Ldiag = ws + o; o += (size_t)NB;
  float* zr = ws + o;
  float* sumexp = zr;                      // 3*NB
  float* rowsum = zr + 3 * NB;             // NB
  float* colsum = rowsum + NB;             // NB
  float* lossv  = colsum + NB;             // 1

  hipMemsetAsync(zr, 0, (size_t)(5 * NB + 1) * sizeof(float), stream);

  diag_teve<<<NB, 64, 0, stream>>>(obj, txt, diagmax, obji8, argi8, tenb, venb);
  const int nxb = NB * 8 / 256, nyb = NB * 3 / 256;    // 40, 15
  wpg_gemm_i8<<<nxb * nyb, 512, 0, stream>>>(argi8, obji8, sumexp, nxb);
  ec_gemm_mfma<<<dim3(NB / 128, NB / 128), 256, 0, stream>>>(tenb, venb, rowsum, colsum, Ldiag);
  lossv_kernel<<<NB, 64, 0, stream>>>(mdl, lab, lossv, C);
  finalize_kernel<<<1, 256, 0, stream>>>(sumexp, diagmax, rowsum, colsum, Ldiag, lossv,
                                         (float*)d_out, NB);
}